// Round 12
// baseline (59.631 us; speedup 1.0000x reference)
//
#include <hip/hip_runtime.h>
#include <math.h>

#define DD  256
#define LKK 512
#define LQQ 256
#define BB  4

constexpr float TWO_LOG2E = 2.8853900817779268f;  // 2*log2(e)
constexpr float LOG2E     = 1.4426950408889634f;
constexpr float CLAMPV    = 1e8f;                  // cap 1+Ea*Eb: tanh err ~2e-8, den<=1e32

__device__ __forceinline__ float fast_rcp(float x)  { return __builtin_amdgcn_rcpf(x); }
__device__ __forceinline__ float fast_exp2(float x) { return __builtin_amdgcn_exp2f(x); }

#define COMP(v,u) ((u)==0?(v).x:(u)==1?(v).y:(u)==2?(v).z:(v).w)

// EaT[b][e][k] = exp(2 * key[b,k,:] . W1[e,:])  (d-major / transposed)
// Eb [b*LQ+q][e] = exp(2 * query[b,q,:] . W2[e,:])  (row-major)
// R9 shape (measured-good): 32-row m-tiles x 64 e, (96,4) grid, acc 2x4.
__global__ __launch_bounds__(256) void gemm_expk2(const float* __restrict__ key,
                                                  const float* __restrict__ query,
                                                  const float* __restrict__ W1,
                                                  const float* __restrict__ W2,
                                                  float* __restrict__ EaT,
                                                  float* __restrict__ Eb) {
  __shared__ float Xs[16][36];
  __shared__ float Ws[16][68];
  const int tid = threadIdx.x;
  const bool isK = blockIdx.x < (BB * LKK / 32);
  const float* __restrict__ X = isK ? key : query;
  const float* __restrict__ W = isK ? W1 : W2;
  const int m0 = (isK ? blockIdx.x : blockIdx.x - BB * LKK / 32) * 32;
  const int e0 = blockIdx.y * 64;

  const int r0 = (tid >> 4) << 1;   // 0..30
  const int c0 = (tid & 15) << 2;   // 0..60
  const int xr = tid >> 3, xc = (tid & 7) << 1;
  const int wr = tid >> 2, wc = (tid & 3) << 2;

  float2 xv = *(const float2*)&X[(m0 + xr) * DD + xc];
  float4 wv = *(const float4*)&W[(e0 + wr) * DD + wc];

  float acc[2][4] = {};
  for (int k0 = 0; k0 < DD; k0 += 16) {
    __syncthreads();
    Xs[xc][xr] = xv.x; Xs[xc + 1][xr] = xv.y;
    Ws[wc][wr] = wv.x; Ws[wc + 1][wr] = wv.y; Ws[wc + 2][wr] = wv.z; Ws[wc + 3][wr] = wv.w;
    __syncthreads();
    if (k0 + 16 < DD) {
      xv = *(const float2*)&X[(m0 + xr) * DD + k0 + 16 + xc];
      wv = *(const float4*)&W[(e0 + wr) * DD + k0 + 16 + wc];
    }
#pragma unroll
    for (int k = 0; k < 16; ++k) {
      const float2 a  = *(const float2*)&Xs[k][r0];
      const float4 bq = *(const float4*)&Ws[k][c0];
      acc[0][0] = fmaf(a.x, bq.x, acc[0][0]); acc[0][1] = fmaf(a.x, bq.y, acc[0][1]);
      acc[0][2] = fmaf(a.x, bq.z, acc[0][2]); acc[0][3] = fmaf(a.x, bq.w, acc[0][3]);
      acc[1][0] = fmaf(a.y, bq.x, acc[1][0]); acc[1][1] = fmaf(a.y, bq.y, acc[1][1]);
      acc[1][2] = fmaf(a.y, bq.z, acc[1][2]); acc[1][3] = fmaf(a.y, bq.w, acc[1][3]);
    }
  }
  if (isK) {
    const int b = m0 >> 9;
    const int kloc = (m0 & 511) + r0;
#pragma unroll
    for (int j = 0; j < 4; ++j) {
      float2 o;
      o.x = fast_exp2(acc[0][j] * TWO_LOG2E);
      o.y = fast_exp2(acc[1][j] * TWO_LOG2E);
      *(float2*)&EaT[b * (DD * LKK) + (e0 + c0 + j) * LKK + kloc] = o;
    }
  } else {
#pragma unroll
    for (int i = 0; i < 2; ++i) {
      float4 o;
      o.x = fast_exp2(acc[i][0] * TWO_LOG2E);
      o.y = fast_exp2(acc[i][1] * TWO_LOG2E);
      o.z = fast_exp2(acc[i][2] * TWO_LOG2E);
      o.w = fast_exp2(acc[i][3] * TWO_LOG2E);
      *(float4*)&Eb[(m0 + r0 + i) * DD + e0 + c0] = o;
    }
  }
}

// One quad = sum_{i=0..3} v_i/A_i with ONE rcp:
//   [(v0*B+v1*A)*CD + (v2*D+v3*C)*AB] / (AB*CD),  A..D = min(1+Ea*Eb, CLAMPV)
#define QUAD(CX, UB, ACC) do {                                        \
    const float A_  = fminf(fmaf(c0.CX, (UB).x, 1.f), CLAMPV);        \
    const float B_  = fminf(fmaf(c1.CX, (UB).y, 1.f), CLAMPV);        \
    const float C_  = fminf(fmaf(c2.CX, (UB).z, 1.f), CLAMPV);        \
    const float D_  = fminf(fmaf(c3.CX, (UB).w, 1.f), CLAMPV);        \
    const float AB_ = A_ * B_, CD_ = C_ * D_;                         \
    const float t1_ = fmaf(uvv.y, A_, uvv.x * B_);                    \
    const float t2_ = fmaf(uvv.w, C_, uvv.z * D_);                    \
    const float nm_ = fmaf(t1_, CD_, t2_ * AB_);                      \
    ACC = fmaf(nm_, fast_rcp(AB_ * CD_), ACC);                        \
  } while (0)

// Fused: quad-rcp scores (d-split across 2 wave-groups) -> softmax -> context.
// 512 blocks x 512 thr = 4 waves/SIMD. Block = (b, 2 q-rows);
// phase-1 thread = (2k x 2q x 128-d half). Wave-uniform dh branches (no div cost).
__global__ __launch_bounds__(512) void attn_fused(const float* __restrict__ EaT,
                                                  const float* __restrict__ Eb,
                                                  const float* __restrict__ vvec,
                                                  const float* __restrict__ value,
                                                  const int* __restrict__ mask,
                                                  float* __restrict__ ctx_out,
                                                  float* __restrict__ attn_out) {
  __shared__ float sc[2][LKK];       // 4 KB (scores, then probs)
  __shared__ float part[2][LKK];     // 4 KB (d-half-1 partials)
  __shared__ float scr[8][2][DD];    // 16 KB (context k-partials)
  __shared__ float redm[2][4], reds[2][4];

  const int tid = threadIdx.x;
  const int bid = blockIdx.x;        // 0..511
  const int b  = bid >> 7;
  const int q0 = (bid & 127) << 1;
  const int dh = tid >> 8;           // 0,1 (wave-uniform)
  const int t  = tid & 255;
  const int k2 = t << 1;             // 0..510
  const int db = dh << 7;            // 0 or 128

  const float* __restrict__ eb0 = &Eb[(b * LQQ + q0) * DD];
  const float* __restrict__ eb1 = eb0 + DD;

  // ---- phase 1: scores (2k x 2q) over this wave-group's 128-d half ----
  {
    const float* __restrict__ ea = &EaT[b * (DD * LKK) + db * LKK + k2];
    float a00 = 0.f, a01 = 0.f, a10 = 0.f, a11 = 0.f;  // [k-lane][q]

    float2 c0 = *(const float2*)&ea[0 * LKK];
    float2 c1 = *(const float2*)&ea[1 * LKK];
    float2 c2 = *(const float2*)&ea[2 * LKK];
    float2 c3 = *(const float2*)&ea[3 * LKK];
    float4 ub0 = *(const float4*)&eb0[db];
    float4 ub1 = *(const float4*)&eb1[db];
    float4 uvv = *(const float4*)&vvec[db];

    for (int d = 0; d < 124; d += 4) {
      const float2 n0 = *(const float2*)&ea[(d + 4) * LKK];
      const float2 n1 = *(const float2*)&ea[(d + 5) * LKK];
      const float2 n2 = *(const float2*)&ea[(d + 6) * LKK];
      const float2 n3 = *(const float2*)&ea[(d + 7) * LKK];
      const float4 nb0 = *(const float4*)&eb0[db + d + 4];
      const float4 nb1 = *(const float4*)&eb1[db + d + 4];
      const float4 nvv = *(const float4*)&vvec[db + d + 4];
      QUAD(x, ub0, a00);
      QUAD(y, ub0, a10);
      QUAD(x, ub1, a01);
      QUAD(y, ub1, a11);
      c0 = n0; c1 = n1; c2 = n2; c3 = n3;
      ub0 = nb0; ub1 = nb1; uvv = nvv;
    }
    QUAD(x, ub0, a00);
    QUAD(y, ub0, a10);
    QUAD(x, ub1, a01);
    QUAD(y, ub1, a11);

    if (dh == 1) {                  // wave-uniform branch
      *(float2*)&part[0][k2] = make_float2(a00, a10);
      *(float2*)&part[1][k2] = make_float2(a01, a11);
    }
    __syncthreads();
    if (dh == 0) {
      // Sv = sum_d v[d] (uniform reads)
      float Sv = 0.f;
#pragma unroll
      for (int d4 = 0; d4 < DD; d4 += 4) {
        const float4 vv = *(const float4*)&vvec[d4];
        Sv += (vv.x + vv.y) + (vv.z + vv.w);
      }
      const float2 p0 = *(const float2*)&part[0][k2];
      const float2 p1 = *(const float2*)&part[1][k2];
      const float inv_scale = 0.0625f;  // 1/sqrt(256)
      float2 s0, s1;                    // per q-row, (k2, k2+1)
      s0.x = (Sv - 2.f * (a00 + p0.x)) * inv_scale;
      s0.y = (Sv - 2.f * (a10 + p0.y)) * inv_scale;
      s1.x = (Sv - 2.f * (a01 + p1.x)) * inv_scale;
      s1.y = (Sv - 2.f * (a11 + p1.y)) * inv_scale;
      const int row0 = (b * LQQ + q0) * LKK + k2;
      const int2 m0 = *(const int2*)&mask[row0];
      const int2 m1 = *(const int2*)&mask[row0 + LKK];
      if (m0.x == 0) s0.x = -1e10f;
      if (m0.y == 0) s0.y = -1e10f;
      if (m1.x == 0) s1.x = -1e10f;
      if (m1.y == 0) s1.y = -1e10f;
      *(float2*)&sc[0][k2] = s0;
      *(float2*)&sc[1][k2] = s1;
    }
  }
  __syncthreads();

  // ---- phase 2: softmax (4 waves per q-row, 2 elems per thread) ----
  {
    const int q = tid >> 8, j = tid & 255;
    const int w4 = (tid >> 6) & 3;
    float x0 = sc[q][j], x1 = sc[q][j + 256];
    float mx = fmaxf(x0, x1);
#pragma unroll
    for (int off = 32; off; off >>= 1) mx = fmaxf(mx, __shfl_xor(mx, off));
    if ((tid & 63) == 0) redm[q][w4] = mx;
    __syncthreads();
    mx = fmaxf(fmaxf(redm[q][0], redm[q][1]), fmaxf(redm[q][2], redm[q][3]));
    float p0 = fast_exp2((x0 - mx) * LOG2E);
    float p1 = fast_exp2((x1 - mx) * LOG2E);
    float sum = p0 + p1;
#pragma unroll
    for (int off = 32; off; off >>= 1) sum += __shfl_xor(sum, off);
    if ((tid & 63) == 0) reds[q][w4] = sum;
    __syncthreads();
    sum = (reds[q][0] + reds[q][1]) + (reds[q][2] + reds[q][3]);
    const float inv = fast_rcp(sum);
    p0 *= inv; p1 *= inv;
    const int arow = (b * LQQ + q0 + q) * LKK + j;
    attn_out[arow]       = p0;
    attn_out[arow + 256] = p1;
    sc[q][j]       = p0;
    sc[q][j + 256] = p1;
  }
  __syncthreads();

  // ---- phase 3: context (thread = k-eighth x float4 d, both q; LDS reduce) ----
  {
    const int kh = tid >> 6, dv = (tid & 63) << 2;
    const int kb = kh << 6;          // 64-k range
    float4 c0 = make_float4(0.f, 0.f, 0.f, 0.f);
    float4 c1 = make_float4(0.f, 0.f, 0.f, 0.f);
    const float* __restrict__ vb = &value[(b * LKK + kb) * DD + dv];
    for (int s = 0; s < 64; s += 4) {
      const float4 p0v = *(const float4*)&sc[0][kb + s];
      const float4 p1v = *(const float4*)&sc[1][kb + s];
#pragma unroll
      for (int u = 0; u < 4; ++u) {
        const float4 vv = *(const float4*)vb; vb += DD;
        const float a0 = COMP(p0v, u), a1 = COMP(p1v, u);
        c0.x = fmaf(a0, vv.x, c0.x); c0.y = fmaf(a0, vv.y, c0.y);
        c0.z = fmaf(a0, vv.z, c0.z); c0.w = fmaf(a0, vv.w, c0.w);
        c1.x = fmaf(a1, vv.x, c1.x); c1.y = fmaf(a1, vv.y, c1.y);
        c1.z = fmaf(a1, vv.z, c1.z); c1.w = fmaf(a1, vv.w, c1.w);
      }
    }
    *(float4*)&scr[kh][0][dv] = c0;
    *(float4*)&scr[kh][1][dv] = c1;
  }
  __syncthreads();

  if (tid < 128) {
    const int qq = tid >> 6, d4 = (tid & 63) << 2;
    float4 s4 = make_float4(0.f, 0.f, 0.f, 0.f);
#pragma unroll
    for (int kh2 = 0; kh2 < 8; ++kh2) {
      const float4 rr = *(const float4*)&scr[kh2][qq][d4];
      s4.x += rr.x; s4.y += rr.y; s4.z += rr.z; s4.w += rr.w;
    }
    *(float4*)&ctx_out[(b * LQQ + q0 + qq) * DD + d4] = s4;
  }
}

extern "C" void kernel_launch(void* const* d_in, const int* in_sizes, int n_in,
                              void* d_out, int out_size, void* d_ws, size_t ws_size,
                              hipStream_t stream) {
  const float* query = (const float*)d_in[0];
  const float* key   = (const float*)d_in[1];
  const float* value = (const float*)d_in[2];
  const float* W1    = (const float*)d_in[3];
  const float* W2    = (const float*)d_in[4];
  const float* v     = (const float*)d_in[5];
  const int*   mask  = (const int*)d_in[6];

  float* out      = (float*)d_out;
  float* ctx_out  = out;                       // [B, LQ, D]
  float* attn_out = out + BB * LQQ * DD;       // [B, LQ, LK]

  float* EaT = (float*)d_ws;                   // [B][D][LK] = 2 MB
  float* Eb  = EaT + BB * DD * LKK;            // [B*LQ][D]  = 1 MB

  dim3 g1(BB * LKK / 32 + BB * LQQ / 32, DD / 64);   // (96, 4)
  gemm_expk2<<<g1, 256, 0, stream>>>(key, query, W1, W2, EaT, Eb);

  attn_fused<<<512, 512, 0, stream>>>(EaT, Eb, v, value, mask, ctx_out, attn_out);
}

// Round 13
// 50.203 us; speedup vs baseline: 1.1878x; 1.1878x over previous
//
#include <hip/hip_runtime.h>
#include <math.h>

#define DD  256
#define LKK 512
#define LQQ 256
#define BB  4

constexpr float TWO_LOG2E = 2.8853900817779268f;  // 2*log2(e)
constexpr float LOG2E     = 1.4426950408889634f;
constexpr float CLAMPV    = 1e8f;                  // cap 1+Ea*Eb: tanh err ~2e-8, den<=1e32

__device__ __forceinline__ float fast_rcp(float x)  { return __builtin_amdgcn_rcpf(x); }
__device__ __forceinline__ float fast_exp2(float x) { return __builtin_amdgcn_exp2f(x); }

#define COMP(v,u) ((u)==0?(v).x:(u)==1?(v).y:(u)==2?(v).z:(v).w)

// EaT[b][e][k] = exp(2 * key[b,k,:] . W1[e,:])  (d-major / transposed)
// Eb [b*LQ+q][e] = exp(2 * query[b,q,:] . W2[e,:])  (row-major)
// R9 shape (measured-good): 32-row m-tiles x 64 e, (96,4) grid, acc 2x4.
__global__ __launch_bounds__(256) void gemm_expk2(const float* __restrict__ key,
                                                  const float* __restrict__ query,
                                                  const float* __restrict__ W1,
                                                  const float* __restrict__ W2,
                                                  float* __restrict__ EaT,
                                                  float* __restrict__ Eb) {
  __shared__ float Xs[16][36];
  __shared__ float Ws[16][68];
  const int tid = threadIdx.x;
  const bool isK = blockIdx.x < (BB * LKK / 32);
  const float* __restrict__ X = isK ? key : query;
  const float* __restrict__ W = isK ? W1 : W2;
  const int m0 = (isK ? blockIdx.x : blockIdx.x - BB * LKK / 32) * 32;
  const int e0 = blockIdx.y * 64;

  const int r0 = (tid >> 4) << 1;   // 0..30
  const int c0 = (tid & 15) << 2;   // 0..60
  const int xr = tid >> 3, xc = (tid & 7) << 1;
  const int wr = tid >> 2, wc = (tid & 3) << 2;

  float2 xv = *(const float2*)&X[(m0 + xr) * DD + xc];
  float4 wv = *(const float4*)&W[(e0 + wr) * DD + wc];

  float acc[2][4] = {};
  for (int k0 = 0; k0 < DD; k0 += 16) {
    __syncthreads();
    Xs[xc][xr] = xv.x; Xs[xc + 1][xr] = xv.y;
    Ws[wc][wr] = wv.x; Ws[wc + 1][wr] = wv.y; Ws[wc + 2][wr] = wv.z; Ws[wc + 3][wr] = wv.w;
    __syncthreads();
    if (k0 + 16 < DD) {
      xv = *(const float2*)&X[(m0 + xr) * DD + k0 + 16 + xc];
      wv = *(const float4*)&W[(e0 + wr) * DD + k0 + 16 + wc];
    }
#pragma unroll
    for (int k = 0; k < 16; ++k) {
      const float2 a  = *(const float2*)&Xs[k][r0];
      const float4 bq = *(const float4*)&Ws[k][c0];
      acc[0][0] = fmaf(a.x, bq.x, acc[0][0]); acc[0][1] = fmaf(a.x, bq.y, acc[0][1]);
      acc[0][2] = fmaf(a.x, bq.z, acc[0][2]); acc[0][3] = fmaf(a.x, bq.w, acc[0][3]);
      acc[1][0] = fmaf(a.y, bq.x, acc[1][0]); acc[1][1] = fmaf(a.y, bq.y, acc[1][1]);
      acc[1][2] = fmaf(a.y, bq.z, acc[1][2]); acc[1][3] = fmaf(a.y, bq.w, acc[1][3]);
    }
  }
  if (isK) {
    const int b = m0 >> 9;
    const int kloc = (m0 & 511) + r0;
#pragma unroll
    for (int j = 0; j < 4; ++j) {
      float2 o;
      o.x = fast_exp2(acc[0][j] * TWO_LOG2E);
      o.y = fast_exp2(acc[1][j] * TWO_LOG2E);
      *(float2*)&EaT[b * (DD * LKK) + (e0 + c0 + j) * LKK + kloc] = o;
    }
  } else {
#pragma unroll
    for (int i = 0; i < 2; ++i) {
      float4 o;
      o.x = fast_exp2(acc[i][0] * TWO_LOG2E);
      o.y = fast_exp2(acc[i][1] * TWO_LOG2E);
      o.z = fast_exp2(acc[i][2] * TWO_LOG2E);
      o.w = fast_exp2(acc[i][3] * TWO_LOG2E);
      *(float4*)&Eb[(m0 + r0 + i) * DD + e0 + c0] = o;
    }
  }
}

// One quad = sum_{i=0..3} v_i/A_i with ONE rcp:
//   [(v0*B+v1*A)*CD + (v2*D+v3*C)*AB] / (AB*CD),  A..D = min(1+Ea*Eb, CLAMPV)
#define QUAD(CX, UB, ACC) do {                                        \
    const float A_  = fminf(fmaf(c0.CX, (UB).x, 1.f), CLAMPV);        \
    const float B_  = fminf(fmaf(c1.CX, (UB).y, 1.f), CLAMPV);        \
    const float C_  = fminf(fmaf(c2.CX, (UB).z, 1.f), CLAMPV);        \
    const float D_  = fminf(fmaf(c3.CX, (UB).w, 1.f), CLAMPV);        \
    const float AB_ = A_ * B_, CD_ = C_ * D_;                         \
    const float t1_ = fmaf(uvv.y, A_, uvv.x * B_);                    \
    const float t2_ = fmaf(uvv.w, C_, uvv.z * D_);                    \
    const float nm_ = fmaf(t1_, CD_, t2_ * AB_);                      \
    ACC = fmaf(nm_, fast_rcp(AB_ * CD_), ACC);                        \
  } while (0)

// Fused: quad-rcp scores, 4 q-rows/block (halved VMEM & L2 per unit work),
// d-split across 2 wave-groups. 256 blocks x 512 thr. Block = (b, 4 q-rows);
// phase-1 thread = (2k x 4q x 128-d half).
__global__ __launch_bounds__(512) void attn_fused(const float* __restrict__ EaT,
                                                  const float* __restrict__ Eb,
                                                  const float* __restrict__ vvec,
                                                  const float* __restrict__ value,
                                                  const int* __restrict__ mask,
                                                  float* __restrict__ ctx_out,
                                                  float* __restrict__ attn_out) {
  __shared__ float sc[4][LKK];       // 8 KB (scores, then probs)
  __shared__ float part[4][LKK];     // 8 KB (d-half-1 partials)
  __shared__ float scr[8][4][DD];    // 32 KB (context k-partials)

  const int tid = threadIdx.x;
  const int bid = blockIdx.x;        // 0..255
  const int b  = bid >> 6;
  const int q0 = (bid & 63) << 2;
  const int dh = tid >> 8;           // 0,1 (wave-uniform)
  const int t  = tid & 255;
  const int k2 = t << 1;             // 0..510
  const int db = dh << 7;            // 0 or 128

  const float* __restrict__ eb0 = &Eb[(b * LQQ + q0) * DD];
  const float* __restrict__ eb1 = eb0 + DD;
  const float* __restrict__ eb2 = eb0 + 2 * DD;
  const float* __restrict__ eb3 = eb0 + 3 * DD;

  // ---- phase 1: scores (2k x 4q) over this wave-group's 128-d half ----
  {
    const float* __restrict__ ea = &EaT[b * (DD * LKK) + db * LKK + k2];
    float a00 = 0.f, a10 = 0.f;   // k-lane {x,y} for q0+0
    float a01 = 0.f, a11 = 0.f;   // q0+1
    float a02 = 0.f, a12 = 0.f;   // q0+2
    float a03 = 0.f, a13 = 0.f;   // q0+3

    float2 c0 = *(const float2*)&ea[0 * LKK];
    float2 c1 = *(const float2*)&ea[1 * LKK];
    float2 c2 = *(const float2*)&ea[2 * LKK];
    float2 c3 = *(const float2*)&ea[3 * LKK];
    float4 ub0 = *(const float4*)&eb0[db];
    float4 ub1 = *(const float4*)&eb1[db];
    float4 ub2 = *(const float4*)&eb2[db];
    float4 ub3 = *(const float4*)&eb3[db];
    float4 uvv = *(const float4*)&vvec[db];

    for (int d = 0; d < 124; d += 4) {
      // issue next chunk's loads first; latency hides under the 8 quads below
      const float2 n0 = *(const float2*)&ea[(d + 4) * LKK];
      const float2 n1 = *(const float2*)&ea[(d + 5) * LKK];
      const float2 n2 = *(const float2*)&ea[(d + 6) * LKK];
      const float2 n3 = *(const float2*)&ea[(d + 7) * LKK];
      const float4 nb0 = *(const float4*)&eb0[db + d + 4];
      const float4 nb1 = *(const float4*)&eb1[db + d + 4];
      const float4 nb2 = *(const float4*)&eb2[db + d + 4];
      const float4 nb3 = *(const float4*)&eb3[db + d + 4];
      const float4 nvv = *(const float4*)&vvec[db + d + 4];
      QUAD(x, ub0, a00); QUAD(y, ub0, a10);
      QUAD(x, ub1, a01); QUAD(y, ub1, a11);
      QUAD(x, ub2, a02); QUAD(y, ub2, a12);
      QUAD(x, ub3, a03); QUAD(y, ub3, a13);
      c0 = n0; c1 = n1; c2 = n2; c3 = n3;
      ub0 = nb0; ub1 = nb1; ub2 = nb2; ub3 = nb3; uvv = nvv;
    }
    QUAD(x, ub0, a00); QUAD(y, ub0, a10);
    QUAD(x, ub1, a01); QUAD(y, ub1, a11);
    QUAD(x, ub2, a02); QUAD(y, ub2, a12);
    QUAD(x, ub3, a03); QUAD(y, ub3, a13);

    if (dh == 1) {                  // wave-uniform branch
      *(float2*)&part[0][k2] = make_float2(a00, a10);
      *(float2*)&part[1][k2] = make_float2(a01, a11);
      *(float2*)&part[2][k2] = make_float2(a02, a12);
      *(float2*)&part[3][k2] = make_float2(a03, a13);
    }
    __syncthreads();
    if (dh == 0) {
      float Sv = 0.f;
#pragma unroll
      for (int d4 = 0; d4 < DD; d4 += 4) {
        const float4 vv = *(const float4*)&vvec[d4];
        Sv += (vv.x + vv.y) + (vv.z + vv.w);
      }
      const float inv_scale = 0.0625f;  // 1/sqrt(256)
      float accx[4] = {a00, a01, a02, a03};
      float accy[4] = {a10, a11, a12, a13};
#pragma unroll
      for (int q = 0; q < 4; ++q) {
        const float2 p = *(const float2*)&part[q][k2];
        float2 s;
        s.x = (Sv - 2.f * (accx[q] + p.x)) * inv_scale;
        s.y = (Sv - 2.f * (accy[q] + p.y)) * inv_scale;
        const int2 mq = *(const int2*)&mask[(b * LQQ + q0 + q) * LKK + k2];
        if (mq.x == 0) s.x = -1e10f;
        if (mq.y == 0) s.y = -1e10f;
        *(float2*)&sc[q][k2] = s;
      }
    }
  }
  __syncthreads();

  // ---- phase 2: softmax (wave w<4 handles q-row w, 8 elems/lane, in-wave) ----
  {
    const int w = tid >> 6, lane = tid & 63;
    if (w < 4) {
      float e_[8];
      float mx = -3.4e38f;
#pragma unroll
      for (int i = 0; i < 8; ++i) { e_[i] = sc[w][(i << 6) + lane]; mx = fmaxf(mx, e_[i]); }
#pragma unroll
      for (int off = 32; off; off >>= 1) mx = fmaxf(mx, __shfl_xor(mx, off));
      float sum = 0.f;
#pragma unroll
      for (int i = 0; i < 8; ++i) { e_[i] = fast_exp2((e_[i] - mx) * LOG2E); sum += e_[i]; }
#pragma unroll
      for (int off = 32; off; off >>= 1) sum += __shfl_xor(sum, off);
      const float inv = fast_rcp(sum);
      const int arow = (b * LQQ + q0 + w) * LKK;
#pragma unroll
      for (int i = 0; i < 8; ++i) {
        const float p = e_[i] * inv;
        attn_out[arow + (i << 6) + lane] = p;
        sc[w][(i << 6) + lane] = p;
      }
    }
  }
  __syncthreads();

  // ---- phase 3: context (thread = k-eighth x float4 d, 4 q; LDS reduce) ----
  {
    const int kh = tid >> 6, dv = (tid & 63) << 2;
    const int kb = kh << 6;          // 64-k range
    float4 c[4] = {};
    const float* __restrict__ vb = &value[(b * LKK + kb) * DD + dv];
    for (int s = 0; s < 64; s += 4) {
      const float4 p0v = *(const float4*)&sc[0][kb + s];
      const float4 p1v = *(const float4*)&sc[1][kb + s];
      const float4 p2v = *(const float4*)&sc[2][kb + s];
      const float4 p3v = *(const float4*)&sc[3][kb + s];
#pragma unroll
      for (int u = 0; u < 4; ++u) {
        const float4 vv = *(const float4*)vb; vb += DD;
        const float a0 = COMP(p0v, u), a1 = COMP(p1v, u);
        const float a2 = COMP(p2v, u), a3 = COMP(p3v, u);
        c[0].x = fmaf(a0, vv.x, c[0].x); c[0].y = fmaf(a0, vv.y, c[0].y);
        c[0].z = fmaf(a0, vv.z, c[0].z); c[0].w = fmaf(a0, vv.w, c[0].w);
        c[1].x = fmaf(a1, vv.x, c[1].x); c[1].y = fmaf(a1, vv.y, c[1].y);
        c[1].z = fmaf(a1, vv.z, c[1].z); c[1].w = fmaf(a1, vv.w, c[1].w);
        c[2].x = fmaf(a2, vv.x, c[2].x); c[2].y = fmaf(a2, vv.y, c[2].y);
        c[2].z = fmaf(a2, vv.z, c[2].z); c[2].w = fmaf(a2, vv.w, c[2].w);
        c[3].x = fmaf(a3, vv.x, c[3].x); c[3].y = fmaf(a3, vv.y, c[3].y);
        c[3].z = fmaf(a3, vv.z, c[3].z); c[3].w = fmaf(a3, vv.w, c[3].w);
      }
    }
#pragma unroll
    for (int q = 0; q < 4; ++q)
      *(float4*)&scr[kh][q][dv] = c[q];
  }
  __syncthreads();

  if (tid < 256) {
    const int qq = tid >> 6, d4 = (tid & 63) << 2;
    float4 s4 = make_float4(0.f, 0.f, 0.f, 0.f);
#pragma unroll
    for (int kh2 = 0; kh2 < 8; ++kh2) {
      const float4 rr = *(const float4*)&scr[kh2][qq][d4];
      s4.x += rr.x; s4.y += rr.y; s4.z += rr.z; s4.w += rr.w;
    }
    *(float4*)&ctx_out[(b * LQQ + q0 + qq) * DD + d4] = s4;
  }
}

extern "C" void kernel_launch(void* const* d_in, const int* in_sizes, int n_in,
                              void* d_out, int out_size, void* d_ws, size_t ws_size,
                              hipStream_t stream) {
  const float* query = (const float*)d_in[0];
  const float* key   = (const float*)d_in[1];
  const float* value = (const float*)d_in[2];
  const float* W1    = (const float*)d_in[3];
  const float* W2    = (const float*)d_in[4];
  const float* v     = (const float*)d_in[5];
  const int*   mask  = (const int*)d_in[6];

  float* out      = (float*)d_out;
  float* ctx_out  = out;                       // [B, LQ, D]
  float* attn_out = out + BB * LQQ * DD;       // [B, LQ, LK]

  float* EaT = (float*)d_ws;                   // [B][D][LK] = 2 MB
  float* Eb  = EaT + BB * DD * LKK;            // [B*LQ][D]  = 1 MB

  dim3 g1(BB * LKK / 32 + BB * LQQ / 32, DD / 64);   // (96, 4)
  gemm_expk2<<<g1, 256, 0, stream>>>(key, query, W1, W2, EaT, Eb);

  attn_fused<<<256, 512, 0, stream>>>(EaT, Eb, v, value, mask, ctx_out, attn_out);
}

// Round 14
// 46.421 us; speedup vs baseline: 1.2846x; 1.0815x over previous
//
#include <hip/hip_runtime.h>
#include <math.h>

#define DD  256
#define LKK 512
#define LQQ 256
#define BB  4

constexpr float TWO_LOG2E = 2.8853900817779268f;  // 2*log2(e)
constexpr float LOG2E     = 1.4426950408889634f;
constexpr float CLAMPV    = 1e8f;                  // cap 1+Ea*Eb: tanh err ~2e-8, den<=1e32

__device__ __forceinline__ float fast_rcp(float x)  { return __builtin_amdgcn_rcpf(x); }
__device__ __forceinline__ float fast_exp2(float x) { return __builtin_amdgcn_exp2f(x); }

#define COMP(v,u) ((u)==0?(v).x:(u)==1?(v).y:(u)==2?(v).z:(v).w)

// EaT[b][e][k] = exp(2 * key[b,k,:] . W1[e,:])  (d-major / transposed)
// Eb [b*LQ+q][e] = exp(2 * query[b,q,:] . W2[e,:])  (row-major)
// BK=32 (8 k-tiles, half the barriers of the measured-slow BK=16 version).
__global__ __launch_bounds__(256) void gemm_expk2(const float* __restrict__ key,
                                                  const float* __restrict__ query,
                                                  const float* __restrict__ W1,
                                                  const float* __restrict__ W2,
                                                  float* __restrict__ EaT,
                                                  float* __restrict__ Eb) {
  __shared__ float Xs[32][36];
  __shared__ float Ws[32][68];
  const int tid = threadIdx.x;
  const bool isK = blockIdx.x < (BB * LKK / 32);
  const float* __restrict__ X = isK ? key : query;
  const float* __restrict__ W = isK ? W1 : W2;
  const int m0 = (isK ? blockIdx.x : blockIdx.x - BB * LKK / 32) * 32;
  const int e0 = blockIdx.y * 64;

  const int r0 = (tid >> 4) << 1;   // 0..30
  const int c0 = (tid & 15) << 2;   // 0..60
  const int xr = tid >> 3, xc = (tid & 7) << 2;   // 32 rows x 32 k via float4
  const int wr = tid >> 2, wc = (tid & 3) << 3;   // 64 rows x 32 k via 2x float4

  float4 xv  = *(const float4*)&X[(m0 + xr) * DD + xc];
  float4 wv0 = *(const float4*)&W[(e0 + wr) * DD + wc];
  float4 wv1 = *(const float4*)&W[(e0 + wr) * DD + wc + 4];

  float acc[2][4] = {};
  for (int k0 = 0; k0 < DD; k0 += 32) {
    __syncthreads();
    Xs[xc + 0][xr] = xv.x; Xs[xc + 1][xr] = xv.y; Xs[xc + 2][xr] = xv.z; Xs[xc + 3][xr] = xv.w;
    Ws[wc + 0][wr] = wv0.x; Ws[wc + 1][wr] = wv0.y; Ws[wc + 2][wr] = wv0.z; Ws[wc + 3][wr] = wv0.w;
    Ws[wc + 4][wr] = wv1.x; Ws[wc + 5][wr] = wv1.y; Ws[wc + 6][wr] = wv1.z; Ws[wc + 7][wr] = wv1.w;
    __syncthreads();
    if (k0 + 32 < DD) {   // prefetch next k-tile; hides under 256 FMAs below
      xv  = *(const float4*)&X[(m0 + xr) * DD + k0 + 32 + xc];
      wv0 = *(const float4*)&W[(e0 + wr) * DD + k0 + 32 + wc];
      wv1 = *(const float4*)&W[(e0 + wr) * DD + k0 + 32 + wc + 4];
    }
#pragma unroll
    for (int k = 0; k < 32; ++k) {
      const float2 a  = *(const float2*)&Xs[k][r0];
      const float4 bq = *(const float4*)&Ws[k][c0];
      acc[0][0] = fmaf(a.x, bq.x, acc[0][0]); acc[0][1] = fmaf(a.x, bq.y, acc[0][1]);
      acc[0][2] = fmaf(a.x, bq.z, acc[0][2]); acc[0][3] = fmaf(a.x, bq.w, acc[0][3]);
      acc[1][0] = fmaf(a.y, bq.x, acc[1][0]); acc[1][1] = fmaf(a.y, bq.y, acc[1][1]);
      acc[1][2] = fmaf(a.y, bq.z, acc[1][2]); acc[1][3] = fmaf(a.y, bq.w, acc[1][3]);
    }
  }
  if (isK) {
    const int b = m0 >> 9;
    const int kloc = (m0 & 511) + r0;
#pragma unroll
    for (int j = 0; j < 4; ++j) {
      float2 o;
      o.x = fast_exp2(acc[0][j] * TWO_LOG2E);
      o.y = fast_exp2(acc[1][j] * TWO_LOG2E);
      *(float2*)&EaT[b * (DD * LKK) + (e0 + c0 + j) * LKK + kloc] = o;
    }
  } else {
#pragma unroll
    for (int i = 0; i < 2; ++i) {
      float4 o;
      o.x = fast_exp2(acc[i][0] * TWO_LOG2E);
      o.y = fast_exp2(acc[i][1] * TWO_LOG2E);
      o.z = fast_exp2(acc[i][2] * TWO_LOG2E);
      o.w = fast_exp2(acc[i][3] * TWO_LOG2E);
      *(float4*)&Eb[(m0 + r0 + i) * DD + e0 + c0] = o;
    }
  }
}

// One quad = sum over 4 consecutive d of v_d/A_d with ONE rcp.
// c0..c3 = Ea float4 (4 k-lanes) for d+0..d+3; CX selects the k-lane.
#define QUAD4(CX, UB, ACC) do {                                       \
    const float A_  = fminf(fmaf(c0.CX, (UB).x, 1.f), CLAMPV);        \
    const float B_  = fminf(fmaf(c1.CX, (UB).y, 1.f), CLAMPV);        \
    const float C_  = fminf(fmaf(c2.CX, (UB).z, 1.f), CLAMPV);        \
    const float D_  = fminf(fmaf(c3.CX, (UB).w, 1.f), CLAMPV);        \
    const float AB_ = A_ * B_, CD_ = C_ * D_;                         \
    const float t1_ = fmaf(uvv.y, A_, uvv.x * B_);                    \
    const float t2_ = fmaf(uvv.w, C_, uvv.z * D_);                    \
    const float nm_ = fmaf(t1_, CD_, t2_ * AB_);                      \
    ACC = fmaf(nm_, fast_rcp(AB_ * CD_), ACC);                        \
  } while (0)

// Fused: quad-rcp scores (4k x 4q x 64-d quarter per thread; float4 Ea loads)
// -> softmax -> context. 256 blocks x 512 thr. Block = (b, 4 q-rows).
__global__ __launch_bounds__(512) void attn_fused(const float* __restrict__ EaT,
                                                  const float* __restrict__ Eb,
                                                  const float* __restrict__ vvec,
                                                  const float* __restrict__ value,
                                                  const int* __restrict__ mask,
                                                  float* __restrict__ ctx_out,
                                                  float* __restrict__ attn_out) {
  __shared__ float sc[4][LKK];       // 8 KB (scores, then probs)
  __shared__ float part[12 * LKK];   // 24 KB (d-groups 1..3 partials)
  __shared__ float scr[8][4][DD];    // 32 KB (context k-partials)

  const int tid = threadIdx.x;
  const int bid = blockIdx.x;        // 0..255
  const int b  = bid >> 6;
  const int q0 = (bid & 63) << 2;
  const int dh = tid >> 7;           // 0..3 (wave-uniform, 64-d quarter)
  const int t  = tid & 127;
  const int k4 = t << 2;             // 0..508
  const int db = dh << 6;            // 0,64,128,192

  const float* __restrict__ eb0 = &Eb[(b * LQQ + q0) * DD];
  const float* __restrict__ eb1 = eb0 + DD;
  const float* __restrict__ eb2 = eb0 + 2 * DD;
  const float* __restrict__ eb3 = eb0 + 3 * DD;

  // ---- phase 1: scores (4k x 4q) over this wave-group's 64-d quarter ----
  {
    const float* __restrict__ ea = &EaT[b * (DD * LKK) + db * LKK + k4];
    float4 acc[4] = {};   // acc[q] = 4 k-lane accumulators (x..w)

    float4 c0 = *(const float4*)&ea[0 * LKK];
    float4 c1 = *(const float4*)&ea[1 * LKK];
    float4 c2 = *(const float4*)&ea[2 * LKK];
    float4 c3 = *(const float4*)&ea[3 * LKK];
    float4 ub0 = *(const float4*)&eb0[db];
    float4 ub1 = *(const float4*)&eb1[db];
    float4 ub2 = *(const float4*)&eb2[db];
    float4 ub3 = *(const float4*)&eb3[db];
    float4 uvv = *(const float4*)&vvec[db];

    for (int d = 0; d < 60; d += 4) {
      // issue next chunk's loads first; latency hides under the 16 quads below
      const float4 n0 = *(const float4*)&ea[(d + 4) * LKK];
      const float4 n1 = *(const float4*)&ea[(d + 5) * LKK];
      const float4 n2 = *(const float4*)&ea[(d + 6) * LKK];
      const float4 n3 = *(const float4*)&ea[(d + 7) * LKK];
      const float4 nb0 = *(const float4*)&eb0[db + d + 4];
      const float4 nb1 = *(const float4*)&eb1[db + d + 4];
      const float4 nb2 = *(const float4*)&eb2[db + d + 4];
      const float4 nb3 = *(const float4*)&eb3[db + d + 4];
      const float4 nvv = *(const float4*)&vvec[db + d + 4];
      QUAD4(x, ub0, acc[0].x); QUAD4(y, ub0, acc[0].y); QUAD4(z, ub0, acc[0].z); QUAD4(w, ub0, acc[0].w);
      QUAD4(x, ub1, acc[1].x); QUAD4(y, ub1, acc[1].y); QUAD4(z, ub1, acc[1].z); QUAD4(w, ub1, acc[1].w);
      QUAD4(x, ub2, acc[2].x); QUAD4(y, ub2, acc[2].y); QUAD4(z, ub2, acc[2].z); QUAD4(w, ub2, acc[2].w);
      QUAD4(x, ub3, acc[3].x); QUAD4(y, ub3, acc[3].y); QUAD4(z, ub3, acc[3].z); QUAD4(w, ub3, acc[3].w);
      c0 = n0; c1 = n1; c2 = n2; c3 = n3;
      ub0 = nb0; ub1 = nb1; ub2 = nb2; ub3 = nb3; uvv = nvv;
    }
    QUAD4(x, ub0, acc[0].x); QUAD4(y, ub0, acc[0].y); QUAD4(z, ub0, acc[0].z); QUAD4(w, ub0, acc[0].w);
    QUAD4(x, ub1, acc[1].x); QUAD4(y, ub1, acc[1].y); QUAD4(z, ub1, acc[1].z); QUAD4(w, ub1, acc[1].w);
    QUAD4(x, ub2, acc[2].x); QUAD4(y, ub2, acc[2].y); QUAD4(z, ub2, acc[2].z); QUAD4(w, ub2, acc[2].w);
    QUAD4(x, ub3, acc[3].x); QUAD4(y, ub3, acc[3].y); QUAD4(z, ub3, acc[3].z); QUAD4(w, ub3, acc[3].w);

    if (dh != 0) {                  // wave-uniform branch
#pragma unroll
      for (int q = 0; q < 4; ++q)
        *(float4*)&part[((dh - 1) * 4 + q) * LKK + k4] = acc[q];
    }
    __syncthreads();
    if (dh == 0) {
      float Sv = 0.f;
#pragma unroll
      for (int d4 = 0; d4 < DD; d4 += 4) {
        const float4 vv = *(const float4*)&vvec[d4];
        Sv += (vv.x + vv.y) + (vv.z + vv.w);
      }
      const float inv_scale = 0.0625f;  // 1/sqrt(256)
#pragma unroll
      for (int q = 0; q < 4; ++q) {
        const float4 p1 = *(const float4*)&part[(0 * 4 + q) * LKK + k4];
        const float4 p2 = *(const float4*)&part[(1 * 4 + q) * LKK + k4];
        const float4 p3 = *(const float4*)&part[(2 * 4 + q) * LKK + k4];
        float4 s;
        s.x = (Sv - 2.f * (acc[q].x + p1.x + p2.x + p3.x)) * inv_scale;
        s.y = (Sv - 2.f * (acc[q].y + p1.y + p2.y + p3.y)) * inv_scale;
        s.z = (Sv - 2.f * (acc[q].z + p1.z + p2.z + p3.z)) * inv_scale;
        s.w = (Sv - 2.f * (acc[q].w + p1.w + p2.w + p3.w)) * inv_scale;
        const int4 mq = *(const int4*)&mask[(b * LQQ + q0 + q) * LKK + k4];
        if (mq.x == 0) s.x = -1e10f;
        if (mq.y == 0) s.y = -1e10f;
        if (mq.z == 0) s.z = -1e10f;
        if (mq.w == 0) s.w = -1e10f;
        *(float4*)&sc[q][k4] = s;
      }
    }
  }
  __syncthreads();

  // ---- phase 2: softmax (wave w<4 handles q-row w, 8 elems/lane, in-wave) ----
  {
    const int w = tid >> 6, lane = tid & 63;
    if (w < 4) {
      float e_[8];
      float mx = -3.4e38f;
#pragma unroll
      for (int i = 0; i < 8; ++i) { e_[i] = sc[w][(i << 6) + lane]; mx = fmaxf(mx, e_[i]); }
#pragma unroll
      for (int off = 32; off; off >>= 1) mx = fmaxf(mx, __shfl_xor(mx, off));
      float sum = 0.f;
#pragma unroll
      for (int i = 0; i < 8; ++i) { e_[i] = fast_exp2((e_[i] - mx) * LOG2E); sum += e_[i]; }
#pragma unroll
      for (int off = 32; off; off >>= 1) sum += __shfl_xor(sum, off);
      const float inv = fast_rcp(sum);
      const int arow = (b * LQQ + q0 + w) * LKK;
#pragma unroll
      for (int i = 0; i < 8; ++i) {
        const float p = e_[i] * inv;
        attn_out[arow + (i << 6) + lane] = p;
        sc[w][(i << 6) + lane] = p;
      }
    }
  }
  __syncthreads();

  // ---- phase 3: context (thread = k-eighth x float4 d, 4 q; LDS reduce) ----
  {
    const int kh = tid >> 6, dv = (tid & 63) << 2;
    const int kb = kh << 6;          // 64-k range
    float4 c[4] = {};
    const float* __restrict__ vb = &value[(b * LKK + kb) * DD + dv];
    for (int s = 0; s < 64; s += 4) {
      const float4 p0v = *(const float4*)&sc[0][kb + s];
      const float4 p1v = *(const float4*)&sc[1][kb + s];
      const float4 p2v = *(const float4*)&sc[2][kb + s];
      const float4 p3v = *(const float4*)&sc[3][kb + s];
#pragma unroll
      for (int u = 0; u < 4; ++u) {
        const float4 vv = *(const float4*)vb; vb += DD;
        const float a0 = COMP(p0v, u), a1 = COMP(p1v, u);
        const float a2 = COMP(p2v, u), a3 = COMP(p3v, u);
        c[0].x = fmaf(a0, vv.x, c[0].x); c[0].y = fmaf(a0, vv.y, c[0].y);
        c[0].z = fmaf(a0, vv.z, c[0].z); c[0].w = fmaf(a0, vv.w, c[0].w);
        c[1].x = fmaf(a1, vv.x, c[1].x); c[1].y = fmaf(a1, vv.y, c[1].y);
        c[1].z = fmaf(a1, vv.z, c[1].z); c[1].w = fmaf(a1, vv.w, c[1].w);
        c[2].x = fmaf(a2, vv.x, c[2].x); c[2].y = fmaf(a2, vv.y, c[2].y);
        c[2].z = fmaf(a2, vv.z, c[2].z); c[2].w = fmaf(a2, vv.w, c[2].w);
        c[3].x = fmaf(a3, vv.x, c[3].x); c[3].y = fmaf(a3, vv.y, c[3].y);
        c[3].z = fmaf(a3, vv.z, c[3].z); c[3].w = fmaf(a3, vv.w, c[3].w);
      }
    }
#pragma unroll
    for (int q = 0; q < 4; ++q)
      *(float4*)&scr[kh][q][dv] = c[q];
  }
  __syncthreads();

  if (tid < 256) {
    const int qq = tid >> 6, d4 = (tid & 63) << 2;
    float4 s4 = make_float4(0.f, 0.f, 0.f, 0.f);
#pragma unroll
    for (int kh2 = 0; kh2 < 8; ++kh2) {
      const float4 rr = *(const float4*)&scr[kh2][qq][d4];
      s4.x += rr.x; s4.y += rr.y; s4.z += rr.z; s4.w += rr.w;
    }
    *(float4*)&ctx_out[(b * LQQ + q0 + qq) * DD + d4] = s4;
  }
}

extern "C" void kernel_launch(void* const* d_in, const int* in_sizes, int n_in,
                              void* d_out, int out_size, void* d_ws, size_t ws_size,
                              hipStream_t stream) {
  const float* query = (const float*)d_in[0];
  const float* key   = (const float*)d_in[1];
  const float* value = (const float*)d_in[2];
  const float* W1    = (const float*)d_in[3];
  const float* W2    = (const float*)d_in[4];
  const float* v     = (const float*)d_in[5];
  const int*   mask  = (const int*)d_in[6];

  float* out      = (float*)d_out;
  float* ctx_out  = out;                       // [B, LQ, D]
  float* attn_out = out + BB * LQQ * DD;       // [B, LQ, LK]

  float* EaT = (float*)d_ws;                   // [B][D][LK] = 2 MB
  float* Eb  = EaT + BB * DD * LKK;            // [B*LQ][D]  = 1 MB

  dim3 g1(BB * LKK / 32 + BB * LQQ / 32, DD / 64);   // (96, 4)
  gemm_expk2<<<g1, 256, 0, stream>>>(key, query, W1, W2, EaT, Eb);

  attn_fused<<<256, 512, 0, stream>>>(EaT, Eb, v, value, mask, ctx_out, attn_out);
}